// Round 3
// baseline (271.439 us; speedup 1.0000x reference)
//
#include <hip/hip_runtime.h>
#include <hip/hip_bf16.h>
#include <stdint.h>

// Problem constants
#define EDIM 1024
#define NH   16
#define HD   64
#define BB   4
#define SS   2048
#define MROWS (BB*SS)   // 8192

typedef __bf16 bf16x8 __attribute__((ext_vector_type(8)));
typedef __bf16 bf16x4 __attribute__((ext_vector_type(4)));
typedef float  f32x4  __attribute__((ext_vector_type(4)));

__device__ __forceinline__ void async16(const void* g, void* lds) {
    __builtin_amdgcn_global_load_lds((__attribute__((address_space(1))) void*)(g),
                                     (__attribute__((address_space(3))) void*)(lds),
                                     16, 0, 0);
}

__device__ __forceinline__ f32x4 mfma16(bf16x8 a, bf16x8 b, f32x4 c) {
    return __builtin_amdgcn_mfma_f32_16x16x32_bf16(a, b, c, 0, 0, 0);
}

// ---------------- fp32 -> bf16 conversion (vectorized) ----------------
__global__ __launch_bounds__(256) void cvt_kernel(const float* __restrict__ s,
                                                  __bf16* __restrict__ d, int n) {
    int i = (blockIdx.x * 256 + threadIdx.x) * 4;
    if (i < n) {
        float4 v = *reinterpret_cast<const float4*>(s + i);
        bf16x4 o;
        o.x = (__bf16)v.x; o.y = (__bf16)v.y; o.z = (__bf16)v.z; o.w = (__bf16)v.w;
        *reinterpret_cast<bf16x4*>(d + i) = o;
    }
}

// ---------------- GEMM: C[m][n] = sum_k A[m][k]*W[n][k] + bias[n] ----------------
// A: [Mdim,1024] bf16 row-major.  W: [1024,1024] bf16 (n,k) row-major.
// mode 0: dst bf16 at [((b*16+h)*2048+s)*64+d]   (Q or K, b=m>>11,s=m&2047,h=n>>6,d=n&63)
// mode 2: dst bf16 at [((b*16+h)*64+d)*2048+s]   (V transposed)
// mode 3: dst fp32 at [m*1024+n]                 (final output)
__global__ __launch_bounds__(256) void gemm_bt(const __bf16* __restrict__ A,
                                               const __bf16* __restrict__ W,
                                               const float* __restrict__ bias,
                                               void* __restrict__ dst, int mode) {
    __shared__ char As[128 * 64];  // 128 rows x 32 bf16 (64B), XOR-swizzled slots
    __shared__ char Bs[128 * 64];

    const int tid = threadIdx.x;
    const int w = tid >> 6, l = tid & 63;
    const int bm = blockIdx.x * 128, bn = blockIdx.y * 128;
    const int wm = (w >> 1) * 64, wn = (w & 1) * 64;

    f32x4 acc[4][4] = {};

    const int lrow = l & 15;
    const int lslot = l >> 4;

    for (int kt = 0; kt < EDIM / 32; ++kt) {
        const int k0 = kt * 32;
        // stage A and B: 512 16B-chunks each; 2 per thread per matrix
        #pragma unroll
        for (int i = 0; i < 2; ++i) {
            int c = i * 256 + tid;
            int row = c >> 2, cb = c & 3;
            int gk = k0 + ((cb ^ (row & 3)) << 3);   // pre-swizzled global source
            async16(A + (size_t)(bm + row) * EDIM + gk, As + (i * 256 + w * 64) * 16);
            async16(W + (size_t)(bn + row) * EDIM + gk, Bs + (i * 256 + w * 64) * 16);
        }
        __syncthreads();

        bf16x8 af[4], bfr[4];
        #pragma unroll
        for (int mf = 0; mf < 4; ++mf) {
            int row = wm + mf * 16 + lrow;
            af[mf] = *reinterpret_cast<const bf16x8*>(As + row * 64 + ((lslot ^ (row & 3)) << 4));
        }
        #pragma unroll
        for (int nf = 0; nf < 4; ++nf) {
            int row = wn + nf * 16 + lrow;
            bfr[nf] = *reinterpret_cast<const bf16x8*>(Bs + row * 64 + ((lslot ^ (row & 3)) << 4));
        }
        #pragma unroll
        for (int mf = 0; mf < 4; ++mf)
            #pragma unroll
            for (int nf = 0; nf < 4; ++nf)
                acc[mf][nf] = mfma16(af[mf], bfr[nf], acc[mf][nf]);
        __syncthreads();
    }

    // epilogue
    #pragma unroll
    for (int nf = 0; nf < 4; ++nf) {
        int ng = bn + wn + nf * 16 + lrow;
        float bv = bias[ng];
        #pragma unroll
        for (int mf = 0; mf < 4; ++mf) {
            #pragma unroll
            for (int r = 0; r < 4; ++r) {
                int mg = bm + wm + mf * 16 + (l >> 4) * 4 + r;
                float v = acc[mf][nf][r] + bv;
                if (mode == 3) {
                    ((float*)dst)[(size_t)mg * EDIM + ng] = v;
                } else {
                    int b = mg >> 11, s = mg & 2047;
                    int h = ng >> 6, d = ng & 63;
                    size_t idx;
                    if (mode == 2) idx = ((size_t)(b * NH + h) * HD + d) * SS + s;
                    else           idx = ((size_t)(b * NH + h) * SS + s) * HD + d;
                    ((__bf16*)dst)[idx] = (__bf16)v;
                }
            }
        }
    }
}

// ---------------- Flash attention (causal) ----------------
// Q,K: [B,H,S,D] bf16.  Vt: [B,H,D,S] bf16.  Oa: [B,S,H*D] bf16.
// Block: 4 waves, each owns 16 q-rows of a 64-row q-tile. KV tiles of 64.
__global__ __launch_bounds__(256) void attn_kernel(const __bf16* __restrict__ Q,
                                                   const __bf16* __restrict__ K,
                                                   const __bf16* __restrict__ Vt,
                                                   __bf16* __restrict__ Oa) {
    __shared__ char ks[64 * 128];      // K tile: row t (64 d * 2B), swizzled
    __shared__ char vs[64 * 128];      // Vt tile: row d (64 t * 2B), swizzled
    __shared__ char Pl[4][16 * 128];   // per-wave P: row q (64 t * 2B), swizzled

    const int bh = blockIdx.x;   // 0..63
    const int qt = blockIdx.y;   // 0..31
    const int tid = threadIdx.x;
    const int w = tid >> 6, l = tid & 63;
    const int lrow = l & 15, lslot = l >> 4;

    const __bf16* Qp = Q + (size_t)bh * (SS * HD);
    const __bf16* Kp = K + (size_t)bh * (SS * HD);
    const __bf16* Vp = Vt + (size_t)bh * (HD * SS);

    // Q fragments (A operand), held in registers for the whole kernel
    const int qrow = qt * 64 + w * 16 + lrow;
    bf16x8 qf[2];
    qf[0] = *reinterpret_cast<const bf16x8*>(Qp + (size_t)qrow * HD + lslot * 8);
    qf[1] = *reinterpret_cast<const bf16x8*>(Qp + (size_t)qrow * HD + 32 + lslot * 8);

    f32x4 oacc[4] = {};
    float mrow[4] = {-1e30f, -1e30f, -1e30f, -1e30f};
    float lsum[4] = {0.f, 0.f, 0.f, 0.f};

    const int qg0 = qt * 64 + w * 16 + (l >> 4) * 4;  // q-row of acc reg r is qg0+r
    const int ntiles = qt + 1;

    for (int kt = 0; kt < ntiles; ++kt) {
        const int kv0 = kt * 64;
        // stage K tile and Vt tile (512 chunks each, 2 per thread per matrix)
        #pragma unroll
        for (int i = 0; i < 2; ++i) {
            int c = i * 256 + tid;
            int row = c >> 3, cb = c & 7;
            int gs = (cb ^ (row & 7)) << 3;
            async16(Kp + (size_t)(kv0 + row) * HD + gs, ks + (i * 256 + w * 64) * 16);
            async16(Vp + (size_t)row * SS + kv0 + gs, vs + (i * 256 + w * 64) * 16);
        }
        __syncthreads();

        // QK^T: scores D-layout: row q = (l>>4)*4+r, col t = tb*16 + (l&15)
        f32x4 sf[4];
        #pragma unroll
        for (int tb = 0; tb < 4; ++tb) {
            f32x4 s = {};
            #pragma unroll
            for (int kc = 0; kc < 2; ++kc) {
                int row = tb * 16 + lrow;
                int slot = (kc * 4 + lslot) ^ (row & 7);
                bf16x8 kf = *reinterpret_cast<const bf16x8*>(ks + row * 128 + slot * 16);
                s = mfma16(qf[kc], kf, s);
            }
            sf[tb] = s;
        }

        const bool diag = (kt == qt);
        // online softmax, per accumulator row r
        #pragma unroll
        for (int r = 0; r < 4; ++r) {
            float mx = -1e30f;
            #pragma unroll
            for (int tb = 0; tb < 4; ++tb) {
                float v = sf[tb][r] * 0.125f;
                if (diag) {
                    int tg = kv0 + tb * 16 + lrow;
                    if (tg > qg0 + r) v = -1e30f;
                }
                sf[tb][r] = v;
                mx = fmaxf(mx, v);
            }
            mx = fmaxf(mx, __shfl_xor(mx, 1));
            mx = fmaxf(mx, __shfl_xor(mx, 2));
            mx = fmaxf(mx, __shfl_xor(mx, 4));
            mx = fmaxf(mx, __shfl_xor(mx, 8));
            float mnew = fmaxf(mrow[r], mx);
            float alpha = __expf(mrow[r] - mnew);
            float psum = 0.f;
            #pragma unroll
            for (int tb = 0; tb < 4; ++tb) {
                float p = __expf(sf[tb][r] - mnew);
                sf[tb][r] = p;
                psum += p;
            }
            psum += __shfl_xor(psum, 1);
            psum += __shfl_xor(psum, 2);
            psum += __shfl_xor(psum, 4);
            psum += __shfl_xor(psum, 8);
            mrow[r] = mnew;
            lsum[r] = lsum[r] * alpha + psum;
            #pragma unroll
            for (int db = 0; db < 4; ++db) oacc[db][r] *= alpha;
            // write P (bf16) to wave-local LDS, swizzled
            int q = (l >> 4) * 4 + r;
            #pragma unroll
            for (int tb = 0; tb < 4; ++tb) {
                int t = tb * 16 + lrow;
                *reinterpret_cast<__bf16*>(Pl[w] + q * 128 + ((t * 2) ^ ((q & 7) << 4))) =
                    (__bf16)sf[tb][r];
            }
        }

        // PV: oacc[db] += P(16x64) * V(64 x d-block)
        #pragma unroll
        for (int tc = 0; tc < 2; ++tc) {
            int q = lrow;
            int pslot = (tc * 4 + lslot) ^ (q & 7);
            bf16x8 pf = *reinterpret_cast<const bf16x8*>(Pl[w] + q * 128 + pslot * 16);
            #pragma unroll
            for (int db = 0; db < 4; ++db) {
                int vrow = db * 16 + lrow;
                int vslot = (tc * 4 + lslot) ^ (vrow & 7);
                bf16x8 vf = *reinterpret_cast<const bf16x8*>(vs + vrow * 128 + vslot * 16);
                oacc[db] = mfma16(pf, vf, oacc[db]);
            }
        }
        __syncthreads();
    }

    // epilogue: Oa[b, s=q, h*64+d] bf16
    const int b = bh >> 4, h = bh & 15;
    #pragma unroll
    for (int db = 0; db < 4; ++db) {
        #pragma unroll
        for (int r = 0; r < 4; ++r) {
            int q = qg0 + r;
            int d = db * 16 + lrow;
            float v = oacc[db][r] / lsum[r];
            Oa[((size_t)(b * SS + q)) * EDIM + h * HD + d] = (__bf16)v;
        }
    }
}

// ---------------- launch ----------------
extern "C" void kernel_launch(void* const* d_in, const int* in_sizes, int n_in,
                              void* d_out, int out_size, void* d_ws, size_t ws_size,
                              hipStream_t stream) {
    const float* x  = (const float*)d_in[0];
    const float* Wq = (const float*)d_in[1];
    const float* bq = (const float*)d_in[2];
    const float* Wk = (const float*)d_in[3];
    const float* bk = (const float*)d_in[4];
    const float* Wv = (const float*)d_in[5];
    const float* bv = (const float*)d_in[6];
    const float* Wo = (const float*)d_in[7];
    const float* bo = (const float*)d_in[8];

    char* ws = (char*)d_ws;
    const size_t SZ_XB  = (size_t)MROWS * EDIM * 2;       // 16 MB
    const size_t SZ_W   = (size_t)EDIM * EDIM * 2;        // 2 MB
    const size_t SZ_QKV = (size_t)BB * NH * SS * HD * 2;  // 16 MB

    __bf16* xb  = (__bf16*)(ws);
    __bf16* wqb = (__bf16*)(ws + SZ_XB);
    __bf16* wkb = (__bf16*)(ws + SZ_XB + SZ_W);
    __bf16* wvb = (__bf16*)(ws + SZ_XB + 2 * SZ_W);
    __bf16* wob = (__bf16*)(ws + SZ_XB + 3 * SZ_W);
    __bf16* Qb  = (__bf16*)(ws + SZ_XB + 4 * SZ_W);
    __bf16* Kb  = (__bf16*)(ws + SZ_XB + 4 * SZ_W + SZ_QKV);
    __bf16* Vtb = (__bf16*)(ws + SZ_XB + 4 * SZ_W + 2 * SZ_QKV);
    __bf16* Oab = (__bf16*)(ws + SZ_XB + 4 * SZ_W + 3 * SZ_QKV);

    cvt_kernel<<<MROWS * EDIM / 1024, 256, 0, stream>>>(x, xb, MROWS * EDIM);
    cvt_kernel<<<EDIM * EDIM / 1024, 256, 0, stream>>>(Wq, wqb, EDIM * EDIM);
    cvt_kernel<<<EDIM * EDIM / 1024, 256, 0, stream>>>(Wk, wkb, EDIM * EDIM);
    cvt_kernel<<<EDIM * EDIM / 1024, 256, 0, stream>>>(Wv, wvb, EDIM * EDIM);
    cvt_kernel<<<EDIM * EDIM / 1024, 256, 0, stream>>>(Wo, wob, EDIM * EDIM);

    dim3 ggrid(MROWS / 128, EDIM / 128);
    gemm_bt<<<ggrid, 256, 0, stream>>>(xb, wqb, bq, (void*)Qb, 0);
    gemm_bt<<<ggrid, 256, 0, stream>>>(xb, wkb, bk, (void*)Kb, 0);
    gemm_bt<<<ggrid, 256, 0, stream>>>(xb, wvb, bv, (void*)Vtb, 2);

    attn_kernel<<<dim3(BB * NH, SS / 64), 256, 0, stream>>>(Qb, Kb, Vtb, Oab);

    gemm_bt<<<ggrid, 256, 0, stream>>>(Oab, wob, bo, d_out, 3);
}